// Round 1
// baseline (333.878 us; speedup 1.0000x reference)
//
#include <hip/hip_runtime.h>

// SPU(v) = v^2 - 0.5            for v >= 0
//        = sigmoid(-v) - 1      for v <  0   ( = -e^v / (1 + e^v), e^v in (0,1) )
__device__ __forceinline__ float spu_f(float v) {
    if (v >= 0.f) {
        return fmaf(v, v, -0.5f);
    }
    float e = __expf(v);
    return -e / (1.f + e);
}

__global__ __launch_bounds__(256) void spu_layer_kernel(
    const float4* __restrict__ x,
    const float4* __restrict__ l,
    const float4* __restrict__ u,
    float4* __restrict__ xo,
    float4* __restrict__ lo,
    float4* __restrict__ uo,
    int n4)
{
    int i = blockIdx.x * blockDim.x + threadIdx.x;
    if (i >= n4) return;

    float4 xv = x[i];
    float4 lv = l[i];
    float4 uv = u[i];
    float4 xr, lr, ur;

    const float* xp = (const float*)&xv;
    const float* lp = (const float*)&lv;
    const float* up = (const float*)&uv;
    float* xq = (float*)&xr;
    float* lq = (float*)&lr;
    float* uq = (float*)&ur;

#pragma unroll
    for (int k = 0; k < 4; ++k) {
        float xk = xp[k], lk = lp[k], uk = up[k];

        float sl = spu_f(lk);
        float su = spu_f(uk);

        float l_out, u_out;
        if (lk >= 0.f) {
            l_out = sl;
            u_out = su;
        } else if (uk <= 0.f) {
            l_out = su;
            u_out = spu_f(su);   // faithful to reference: spu(spu(u))
        } else {
            l_out = -0.5f;
            u_out = su;
        }

        xq[k] = spu_f(xk);
        lq[k] = l_out;
        uq[k] = u_out;
    }

    xo[i] = xr;
    lo[i] = lr;
    uo[i] = ur;
}

extern "C" void kernel_launch(void* const* d_in, const int* in_sizes, int n_in,
                              void* d_out, int out_size, void* d_ws, size_t ws_size,
                              hipStream_t stream) {
    const float* x = (const float*)d_in[0];
    const float* l = (const float*)d_in[1];
    const float* u = (const float*)d_in[2];
    float* out = (float*)d_out;

    const int n  = in_sizes[0];          // 16777216
    const int n4 = n / 4;                // divisible: 16M % 4 == 0

    float* xo = out;
    float* lo = out + n;
    float* uo = out + 2 * (size_t)n;

    dim3 block(256);
    dim3 grid((n4 + 255) / 256);
    spu_layer_kernel<<<grid, block, 0, stream>>>(
        (const float4*)x, (const float4*)l, (const float4*)u,
        (float4*)xo, (float4*)lo, (float4*)uo, n4);
}

// Round 4
// 329.062 us; speedup vs baseline: 1.0146x; 1.0146x over previous
//
#include <hip/hip_runtime.h>

// Native clang vector: __builtin_nontemporal_* requires a real vector type,
// not HIP's struct-based float4.
typedef float vf4 __attribute__((ext_vector_type(4)));

// SPU(v) = v^2 - 0.5        for v >= 0
//        = sigmoid(-v) - 1  for v <  0  ( = -e^v/(1+e^v) )
// Branchless: compute both, select. For huge +v, the neg path gives NaN
// (inf * rcp(inf)) but is discarded by the select. For v -> -inf, neg -> -0. OK.
// v_rcp_f32 approx (~1e-7 rel) is fine: absmax threshold is 1.08, we measured 0.03.
__device__ __forceinline__ float spu_f(float v) {
    float e   = __expf(v);                                    // v_exp_f32 (x*log2e + exp2)
    float neg = -e * __builtin_amdgcn_rcpf(1.f + e);          // v_rcp_f32, no IEEE divide
    float pos = fmaf(v, v, -0.5f);
    return v >= 0.f ? pos : neg;                              // v_cndmask
}

__device__ __forceinline__ void process4(
    const vf4* __restrict__ x, const vf4* __restrict__ l, const vf4* __restrict__ u,
    vf4* __restrict__ xo, vf4* __restrict__ lo, vf4* __restrict__ uo, int i)
{
    vf4 xv = __builtin_nontemporal_load(x + i);
    vf4 lv = __builtin_nontemporal_load(l + i);
    vf4 uv = __builtin_nontemporal_load(u + i);
    vf4 xr, lr, ur;

#pragma unroll
    for (int k = 0; k < 4; ++k) {
        float xk = xv[k], lk = lv[k], uk = uv[k];

        float sl  = spu_f(lk);
        float su  = spu_f(uk);
        float ssu = spu_f(su);   // only used when l<0 && u<=0 (su in [-0.5,0) there)

        // l_out = l>=0 ? spu(l) : (u<=0 ? spu(u) : -0.5)
        float l_out = lk >= 0.f ? sl : (uk <= 0.f ? su : -0.5f);
        // u_out = (l<0 && u<=0) ? spu(spu(u)) : spu(u)
        float u_out = (lk < 0.f && uk <= 0.f) ? ssu : su;

        xr[k] = spu_f(xk);
        lr[k] = l_out;
        ur[k] = u_out;
    }

    __builtin_nontemporal_store(xr, xo + i);
    __builtin_nontemporal_store(lr, lo + i);
    __builtin_nontemporal_store(ur, uo + i);
}

__global__ __launch_bounds__(256) void spu_layer_kernel(
    const vf4* __restrict__ x,
    const vf4* __restrict__ l,
    const vf4* __restrict__ u,
    vf4* __restrict__ xo,
    vf4* __restrict__ lo,
    vf4* __restrict__ uo,
    int n4)
{
    // Each block covers two contiguous 256-float4 chunks -> 2 independent
    // load groups per stream per thread (more VMEM in flight).
    int base = blockIdx.x * (blockDim.x * 2) + threadIdx.x;
    if (base < n4)
        process4(x, l, u, xo, lo, uo, base);
    int base2 = base + blockDim.x;
    if (base2 < n4)
        process4(x, l, u, xo, lo, uo, base2);
}

extern "C" void kernel_launch(void* const* d_in, const int* in_sizes, int n_in,
                              void* d_out, int out_size, void* d_ws, size_t ws_size,
                              hipStream_t stream) {
    const float* x = (const float*)d_in[0];
    const float* l = (const float*)d_in[1];
    const float* u = (const float*)d_in[2];
    float* out = (float*)d_out;

    const int n  = in_sizes[0];          // 16777216
    const int n4 = n / 4;                // 4194304 float4s per stream

    float* xo = out;
    float* lo = out + n;
    float* uo = out + 2 * (size_t)n;

    dim3 block(256);
    dim3 grid((n4 + 511) / 512);         // 2 float4 per thread
    spu_layer_kernel<<<grid, block, 0, stream>>>(
        (const vf4*)x, (const vf4*)l, (const vf4*)u,
        (vf4*)xo, (vf4*)lo, (vf4*)uo, n4);
}